// Round 1
// baseline (243.078 us; speedup 1.0000x reference)
//
#include <hip/hip_runtime.h>

#define BATCH 512
#define NN    200
#define SIG1  0.73105857863f   // sigmoid(1)
#define SIG0  0.5f             // sigmoid(0)

// Padded LDS index for the u/v/w vectors: spreads the 50-lane ds_add pattern
// (addresses 4*c+k) across all banks (9a+4b+k is collision-free mod 32 for
// a=0..24), and reads are wave-uniform broadcasts anyway.
__device__ __forceinline__ int XA(int m) { return m + (m >> 3); }

// ---------------------------------------------------------------------------
// prep: blocks 0..156: Rs[n][m] = 0.5*(R[n][m]+R[m][n]) + (n==m)   (fp32)
//       block 157:     Wc = W0 @ (W1 @ (W2 @ pw))   [200][2] fp32
__global__ __launch_bounds__(256) void prep(
    const float* __restrict__ R,
    const float* __restrict__ W0, const float* __restrict__ W1,
    const float* __restrict__ W2, const float* __restrict__ pw,
    float* __restrict__ Rs, float* __restrict__ Wc) {
    const int blk = blockIdx.x;
    const int tid = threadIdx.x;
    if (blk < 157) {
        int idx = blk * 256 + tid;
        if (idx < NN * NN) {
            int n = idx / NN, m = idx - n * NN;
            Rs[idx] = 0.5f * (R[idx] + R[m * NN + n]) + (n == m ? 1.f : 0.f);
        }
    } else {
        __shared__ float t0[256], t1[256];
        float a0 = 0.f, a1 = 0.f;
#pragma unroll 16
        for (int c = 0; c < 256; ++c) {
            float w2 = W2[tid * 256 + c];
            a0 += w2 * pw[2 * c];
            a1 += w2 * pw[2 * c + 1];
        }
        t0[tid] = a0; t1[tid] = a1;
        __syncthreads();
        float b0 = 0.f, b1 = 0.f;
#pragma unroll 16
        for (int h = 0; h < 256; ++h) {
            float w1 = W1[tid * 256 + h];
            b0 += w1 * t0[h];
            b1 += w1 * t1[h];
        }
        __syncthreads();
        t0[tid] = b0; t1[tid] = b1;
        __syncthreads();
        if (tid < NN) {
            float c0 = 0.f, c1 = 0.f;
#pragma unroll 16
            for (int o = 0; o < 256; ++o) {
                float w0 = W0[tid * 256 + o];
                c0 += w0 * t0[o];
                c1 += w0 * t1[o];
            }
            Wc[tid * 2 + 0] = c0;
            Wc[tid * 2 + 1] = c1;
        }
    }
}

// ---------------------------------------------------------------------------
// Phase A body: read adj+Rs rows, build per-column adjacency bitmasks,
// accumulate u-partials. NR is compile-time -> full unroll, deep load pipe.
template<int NR>
__device__ __forceinline__ void phase_a(const float* __restrict__ adjr,
                                        const float* __restrict__ rsr,
                                        unsigned& m0, unsigned& m1,
                                        unsigned& m2, unsigned& m3,
                                        float4& acc) {
#pragma unroll
    for (int j = 0; j < NR; ++j) {
        float4 a = *(const float4*)(adjr + j * NN);
        float4 r = *(const float4*)(rsr  + j * NN);
        bool t;
        t = a.x > 0.5f; m0 |= (unsigned)t << j; acc.x += r.x * (t ? SIG1 : SIG0);
        t = a.y > 0.5f; m1 |= (unsigned)t << j; acc.y += r.y * (t ? SIG1 : SIG0);
        t = a.z > 0.5f; m2 |= (unsigned)t << j; acc.z += r.z * (t ? SIG1 : SIG0);
        t = a.w > 0.5f; m3 |= (unsigned)t << j; acc.w += r.w * (t ? SIG1 : SIG0);
    }
}

// Phase B/C body: acc += M^T x over this thread's row slice (Rs from L2,
// adjacency bits from registers, x broadcast from LDS).
template<int NR>
__device__ __forceinline__ void phase_m(const float* __restrict__ rsr,
                                        const float* __restrict__ xsIn, int r0,
                                        unsigned m0, unsigned m1,
                                        unsigned m2, unsigned m3,
                                        float4& acc) {
#pragma unroll
    for (int j = 0; j < NR; ++j) {
        float4 r = *(const float4*)(rsr + j * NN);
        float xn = xsIn[XA(r0 + j)];
        acc.x += r.x * (((m0 >> j) & 1u) ? SIG1 : SIG0) * xn;
        acc.y += r.y * (((m1 >> j) & 1u) ? SIG1 : SIG0) * xn;
        acc.z += r.z * (((m2 >> j) & 1u) ? SIG1 : SIG0) * xn;
        acc.w += r.w * (((m3 >> j) & 1u) ? SIG1 : SIG0) * xn;
    }
}

// ---------------------------------------------------------------------------
// One 1024-thread block per graph. Rank-1 collapsed MaskGCN:
//   u = M^T 1 ; v = M^T u ; w = M^T v ; FW = X @ Wc ; out = (w·FW)/N + pb
// Thread (q = tid>>6: 16 row groups of 13 [last 5], c4 = tid&63: cols 4c4..+3,
// lanes c4>=50 masked off for A/B/C). FW computed in phase A2 (4 threads/row)
// so the feat stream overlaps the adj stream in the same barrier segment.
// Reductions are LDS float atomics (ds_add_f32) into padded vectors: no
// single-wave serial reduce, 5 barriers total instead of 8.
__global__ __launch_bounds__(1024, 8) void gcn_main(
    const float* __restrict__ adj, const float* __restrict__ feat,
    const float* __restrict__ Rs, const float* __restrict__ Wc,
    const float* __restrict__ pb, float* __restrict__ out) {
    const int b   = blockIdx.x;
    const int tid = threadIdx.x;
    const int c4  = tid & 63;
    const int q   = tid >> 6;                  // 0..15, wave-uniform
    const int col0 = (c4 < 50 ? c4 : 49) * 4;  // lanes >=50 are masked anyway
    const int r0  = q * 13;                    // rows r0 .. r0+NR-1
    const float* adjb  = adj  + (size_t)b * NN * NN;
    const float* featb = feat + (size_t)b * NN * NN;

    __shared__ float xs0[224], xs1[224], xs2[224];  // u, v, w (padded XA layout)
    __shared__ float FW[2 * NN];                    // feat @ Wc, [n][2]
    __shared__ float WcL[2 * NN];                   // staged Wc
    __shared__ float oa[2];

    if (tid < 224) { xs0[tid] = 0.f; xs1[tid] = 0.f; xs2[tid] = 0.f; }
    if (tid < 100) *(float4*)(WcL + tid * 4) = *(const float4*)(Wc + tid * 4);
    if (tid == 1023) { oa[0] = 0.f; oa[1] = 0.f; }
    __syncthreads();

    // ---- Phase A: u = M^T 1  (adj stream; capture adjacency bitmasks) ----
    unsigned m0 = 0, m1 = 0, m2 = 0, m3 = 0;
    if (c4 < 50) {
        const float* adjr = adjb + r0 * NN + col0;
        const float* rsr  = Rs   + r0 * NN + col0;
        float4 acc = {0.f, 0.f, 0.f, 0.f};
        if (q < 15) phase_a<13>(adjr, rsr, m0, m1, m2, m3, acc);
        else        phase_a< 5>(adjr, rsr, m0, m1, m2, m3, acc);
        atomicAdd(&xs0[XA(col0 + 0)], acc.x);
        atomicAdd(&xs0[XA(col0 + 1)], acc.y);
        atomicAdd(&xs0[XA(col0 + 2)], acc.z);
        atomicAdd(&xs0[XA(col0 + 3)], acc.w);
    }

    // ---- Phase A2: FW[n][:] = feat[n][:] @ Wc  (feat stream, same segment,
    //      consumed only in phase D -> its latency hides under B/C) ----
    {
        const int t4   = tid & 3;
        const int nrow = tid >> 2;             // 0..255
        if (nrow < NN) {
            const float* fr = featb + nrow * NN;
            float p0 = 0.f, p1 = 0.f;
#pragma unroll
            for (int k = 0; k < 12; ++k) {
                const int cidx = t4 + k * 4;   // 4-thread interleave: 64B/row/instr
                float4 f  = *(const float4*)(fr + cidx * 4);
                float4 wa = *(const float4*)(WcL + cidx * 8);
                float4 wb = *(const float4*)(WcL + cidx * 8 + 4);
                p0 += f.x * wa.x + f.y * wa.z + f.z * wb.x + f.w * wb.z;
                p1 += f.x * wa.y + f.y * wa.w + f.z * wb.y + f.w * wb.w;
            }
            if (t4 < 2) {                      // chunks 48,49
                const int cidx = t4 + 48;
                float4 f  = *(const float4*)(fr + cidx * 4);
                float4 wa = *(const float4*)(WcL + cidx * 8);
                float4 wb = *(const float4*)(WcL + cidx * 8 + 4);
                p0 += f.x * wa.x + f.y * wa.z + f.z * wb.x + f.w * wb.z;
                p1 += f.x * wa.y + f.y * wa.w + f.z * wb.y + f.w * wb.w;
            }
            p0 += __shfl_down(p0, 1); p0 += __shfl_down(p0, 2);
            p1 += __shfl_down(p1, 1); p1 += __shfl_down(p1, 2);
            if (t4 == 0) { FW[nrow * 2] = p0; FW[nrow * 2 + 1] = p1; }
        }
    }
    __syncthreads();   // u in xs0, FW ready

    // ---- Phase B: v = M^T u ----
    if (c4 < 50) {
        const float* rsr = Rs + r0 * NN + col0;
        float4 acc = {0.f, 0.f, 0.f, 0.f};
        if (q < 15) phase_m<13>(rsr, xs0, r0, m0, m1, m2, m3, acc);
        else        phase_m< 5>(rsr, xs0, r0, m0, m1, m2, m3, acc);
        atomicAdd(&xs1[XA(col0 + 0)], acc.x);
        atomicAdd(&xs1[XA(col0 + 1)], acc.y);
        atomicAdd(&xs1[XA(col0 + 2)], acc.z);
        atomicAdd(&xs1[XA(col0 + 3)], acc.w);
    }
    __syncthreads();

    // ---- Phase C: w = M^T v ----
    if (c4 < 50) {
        const float* rsr = Rs + r0 * NN + col0;
        float4 acc = {0.f, 0.f, 0.f, 0.f};
        if (q < 15) phase_m<13>(rsr, xs1, r0, m0, m1, m2, m3, acc);
        else        phase_m< 5>(rsr, xs1, r0, m0, m1, m2, m3, acc);
        atomicAdd(&xs2[XA(col0 + 0)], acc.x);
        atomicAdd(&xs2[XA(col0 + 1)], acc.y);
        atomicAdd(&xs2[XA(col0 + 2)], acc.z);
        atomicAdd(&xs2[XA(col0 + 3)], acc.w);
    }
    __syncthreads();

    // ---- Phase D: out = (w · FW) / N + pb  (200x2 dot, waves 0-3) ----
    if (tid < 256) {
        float p0 = 0.f, p1 = 0.f;
        if (tid < NN) {
            const float wv = xs2[XA(tid)];
            p0 = wv * FW[tid * 2];
            p1 = wv * FW[tid * 2 + 1];
        }
#pragma unroll
        for (int off = 32; off > 0; off >>= 1) {
            p0 += __shfl_down(p0, off);
            p1 += __shfl_down(p1, off);
        }
        if ((tid & 63) == 0) { atomicAdd(&oa[0], p0); atomicAdd(&oa[1], p1); }
    }
    __syncthreads();
    if (tid == 0) {
        out[b * 2 + 0] = oa[0] * (1.f / NN) + pb[0];
        out[b * 2 + 1] = oa[1] * (1.f / NN) + pb[1];
    }
}

// ---------------------------------------------------------------------------
extern "C" void kernel_launch(void* const* d_in, const int* in_sizes, int n_in,
                              void* d_out, int out_size, void* d_ws, size_t ws_size,
                              hipStream_t stream) {
    const float* adj  = (const float*)d_in[0];
    const float* feat = (const float*)d_in[1];
    const float* R    = (const float*)d_in[2];
    const float* W0   = (const float*)d_in[3];
    const float* W1   = (const float*)d_in[4];
    const float* W2   = (const float*)d_in[5];
    const float* pw   = (const float*)d_in[6];
    const float* pb   = (const float*)d_in[7];

    char* ws = (char*)d_ws;
    float* Rs = (float*)(ws);             // 160,000 B
    float* Wc = (float*)(ws + 160000);    // 1,600 B

    prep<<<158, 256, 0, stream>>>(R, W0, W1, W2, pw, Rs, Wc);
    gcn_main<<<BATCH, 1024, 0, stream>>>(adj, feat, Rs, Wc, pb, (float*)d_out);
}